// Round 15
// baseline (795.090 us; speedup 1.0000x reference)
//
#include <hip/hip_runtime.h>

#define N_NODES 100000
#define N_EDGES 1600000
#define HID 256

typedef _Float16 half_t;
using f16x8 = __attribute__((ext_vector_type(8))) half_t;
using f16x4 = __attribute__((ext_vector_type(4))) half_t;
using f32x4 = __attribute__((ext_vector_type(4))) float;

constexpr int SCAN_CHUNK = 1024;
constexpr int NBLK = (N_NODES + SCAN_CHUNK - 1) / SCAN_CHUNK; // 98
constexpr int FILL_EPB = 4096;
constexpr int FILL_CHUNKS = (N_EDGES + FILL_EPB - 1) / FILL_EPB; // 391

#define GLOAD_LDS16(gp, lp)                                                    \
    __builtin_amdgcn_global_load_lds(                                         \
        (const __attribute__((address_space(1))) void*)(gp),                  \
        (__attribute__((address_space(3))) void*)(lp), 16, 0, 0)

template <int N>
__device__ __forceinline__ void vmwait() {
    asm volatile("s_waitcnt vmcnt(%0)" :: "n"(N) : "memory");
}

// ---------------- CSR build ----------------
__global__ __launch_bounds__(256) void k_count_xcd(
    const int* __restrict__ dst, int* __restrict__ deg) {
    const int part = blockIdx.x & 7;
    const int chunk = blockIdx.x >> 3;
    const int lo = part * (N_NODES / 8);
    const int hi = lo + (N_NODES / 8);
    const int ebeg = chunk * FILL_EPB + threadIdx.x;
    const int eend = min((chunk + 1) * FILL_EPB, N_EDGES);
    for (int e = ebeg; e < eend; e += 256) {
        int d = dst[e];
        if (d >= lo && d < hi) atomicAdd(&deg[d], 1);
    }
}

__global__ void k_blocksum(const int* __restrict__ deg, int* __restrict__ bsum) {
    __shared__ int sm[4];
    int b = blockIdx.x, t = threadIdx.x;
    int base = b * SCAN_CHUNK;
    int s = 0;
    for (int i = 0; i < 4; ++i) {
        int idx = base + t + i * 256;
        if (idx < N_NODES) s += deg[idx];
    }
    for (int off = 32; off; off >>= 1) s += __shfl_down(s, off);
    if ((t & 63) == 0) sm[t >> 6] = s;
    __syncthreads();
    if (t == 0) bsum[b] = sm[0] + sm[1] + sm[2] + sm[3];
}

__global__ void k_scan_bsum(const int* __restrict__ bsum, int* __restrict__ bscan) {
    if (threadIdx.x == 0) {
        int r = 0;
        for (int i = 0; i < NBLK; ++i) { bscan[i] = r; r += bsum[i]; }
    }
}

__global__ void k_scan_final(const int* __restrict__ deg, const int* __restrict__ bscan,
                             int* __restrict__ offsets, int* __restrict__ cursor) {
    __shared__ int sm[256];
    int b = blockIdx.x, t = threadIdx.x;
    int base = b * SCAN_CHUNK + t * 4;
    int c[4];
    for (int e = 0; e < 4; ++e) {
        int idx = base + e;
        c[e] = (idx < N_NODES) ? deg[idx] : 0;
    }
    int s = c[0] + c[1] + c[2] + c[3];
    sm[t] = s;
    __syncthreads();
    for (int off = 1; off < 256; off <<= 1) {
        int v = (t >= off) ? sm[t - off] : 0;
        __syncthreads();
        sm[t] += v;
        __syncthreads();
    }
    int run = sm[t] - s + bscan[b];
    for (int e = 0; e < 4; ++e) {
        int idx = base + e;
        if (idx < N_NODES) { offsets[idx] = run; cursor[idx] = run; }
        run += c[e];
    }
}

// XCD-partitioned fill (R10 win)
__global__ __launch_bounds__(256) void k_fill_xcd(
    const int* __restrict__ src, const int* __restrict__ dst,
    int* __restrict__ cursor, int* __restrict__ csr) {
    const int part = blockIdx.x & 7;
    const int chunk = blockIdx.x >> 3;
    const int lo = part * (N_NODES / 8);
    const int hi = lo + (N_NODES / 8);
    const int ebeg = chunk * FILL_EPB + threadIdx.x;
    const int eend = min((chunk + 1) * FILL_EPB, N_EDGES);
    for (int e = ebeg; e < eend; e += 256) {
        int d = dst[e];
        if (d >= lo && d < hi) {
            int pos = atomicAdd(&cursor[d], 1);
            csr[pos] = src[e];
        }
    }
}

// ---------------- fp32 -> fp16 convert ----------------
__global__ void k_tohalf(const float* __restrict__ in, half_t* __restrict__ out, int n8) {
    int i = blockIdx.x * 256 + threadIdx.x;
    if (i < n8) {
        float4 a = *reinterpret_cast<const float4*>(in + (size_t)i * 8);
        float4 b = *reinterpret_cast<const float4*>(in + (size_t)i * 8 + 4);
        f16x8 h;
        h[0] = (half_t)a.x; h[1] = (half_t)a.y; h[2] = (half_t)a.z; h[3] = (half_t)a.w;
        h[4] = (half_t)b.x; h[5] = (half_t)b.y; h[6] = (half_t)b.z; h[7] = (half_t)b.w;
        *reinterpret_cast<f16x8*>(out + (size_t)i * 8) = h;
    }
}

// ---------------- mean aggregation -> fp16 (at line-rate floor) -----------
__global__ __launch_bounds__(256) void k_aggregate_h(
    const half_t* __restrict__ xh, const int* __restrict__ offsets,
    const int* __restrict__ deg, const int* __restrict__ csr,
    half_t* __restrict__ aggH) {
    int wave = threadIdx.x >> 6;
    int lane = threadIdx.x & 63;
    int node = blockIdx.x * 4 + wave;
    int off = offsets[node];
    int dg = deg[node];
    const size_t lo4 = (size_t)lane * 4;
    float4 a0 = {0.f, 0.f, 0.f, 0.f}, a1 = a0, a2 = a0, a3 = a0;
    int j = 0;
    for (; j + 4 <= dg; j += 4) {
        int s0 = csr[off + j + 0];
        int s1 = csr[off + j + 1];
        int s2 = csr[off + j + 2];
        int s3 = csr[off + j + 3];
        f16x4 v0 = *reinterpret_cast<const f16x4*>(xh + (size_t)s0 * HID + lo4);
        f16x4 v1 = *reinterpret_cast<const f16x4*>(xh + (size_t)s1 * HID + lo4);
        f16x4 v2 = *reinterpret_cast<const f16x4*>(xh + (size_t)s2 * HID + lo4);
        f16x4 v3 = *reinterpret_cast<const f16x4*>(xh + (size_t)s3 * HID + lo4);
        a0.x += (float)v0[0]; a0.y += (float)v0[1]; a0.z += (float)v0[2]; a0.w += (float)v0[3];
        a1.x += (float)v1[0]; a1.y += (float)v1[1]; a1.z += (float)v1[2]; a1.w += (float)v1[3];
        a2.x += (float)v2[0]; a2.y += (float)v2[1]; a2.z += (float)v2[2]; a2.w += (float)v2[3];
        a3.x += (float)v3[0]; a3.y += (float)v3[1]; a3.z += (float)v3[2]; a3.w += (float)v3[3];
    }
    for (; j < dg; ++j) {
        int s = csr[off + j];
        f16x4 v = *reinterpret_cast<const f16x4*>(xh + (size_t)s * HID + lo4);
        a0.x += (float)v[0]; a0.y += (float)v[1]; a0.z += (float)v[2]; a0.w += (float)v[3];
    }
    float av[4];
    av[0] = (a0.x + a1.x) + (a2.x + a3.x);
    av[1] = (a0.y + a1.y) + (a2.y + a3.y);
    av[2] = (a0.z + a1.z) + (a2.z + a3.z);
    av[3] = (a0.w + a1.w) + (a2.w + a3.w);
    float inv = 1.0f / (float)(dg > 0 ? dg : 1);
    f16x4 hi;
#pragma unroll
    for (int c = 0; c < 4; ++c) hi[c] = (half_t)(av[c] * inv);
    *reinterpret_cast<f16x4*>(aggH + (size_t)node * HID + lo4) = hi;
}

// ---------------- all weight transposes in ONE launch ----------------------
__global__ void k_transw_all(const float* __restrict__ Wl, const float* __restrict__ Wr,
                             const float* __restrict__ W1, half_t* __restrict__ WT) {
    int b = blockIdx.x;
    int k = threadIdx.x;
    if (b < 768) {
        int l = b >> 8, col = b & 255;
        WT[(size_t)l * 65536 + col * 256 + k] = (half_t)Wl[(size_t)l * 65536 + k * 256 + col];
    } else if (b < 1536) {
        int l = (b - 768) >> 8, col = b & 255;
        WT[(size_t)(3 + l) * 65536 + col * 256 + k] = (half_t)Wr[(size_t)l * 65536 + k * 256 + col];
    } else {
        int col = b - 1536;
        WT[(size_t)6 * 65536 + col * 256 + k] = (half_t)W1[(size_t)k * 128 + col];
    }
}

// ---------------- layer GEMM: 256x128 tile, 2 blocks/CU, single-barrier ----
// C[M][256] = relu(bias + A1@B1 + A2@B2), K=256/op, fp16 in/out, fp32 acc.
// Grid = mtiles*2 (low bit = col-block). 8 waves as 4m x 2n (wave 64x64,
// acc 64 f32 -> ~110 VGPR -> 128-reg bucket -> 4 waves/SIMD). A,B 3-buf
// (48+24=72KB LDS) -> 2 blocks/CU: co-resident block fills barrier stalls.
// Per step t: vmwait<3> (stage t landed; t+1's 3 loads in flight); barrier;
// STAGE(t+2); 16 MFMAs from buf t%3. One barrier/step.
__global__ __launch_bounds__(512, 4) void k_gemm_l(
    const half_t* __restrict__ A1, const half_t* __restrict__ B1,
    const half_t* __restrict__ A2, const half_t* __restrict__ B2,
    const float* __restrict__ bias, half_t* __restrict__ C, int M) {
    constexpr int NSTEPS = 16;
    __shared__ f16x8 sA[3][1024];   // [kg(4)][row(256)]  48KB
    __shared__ f16x8 sB[3][512];    // [kg(4)][col(128)]  24KB

    const int tid = threadIdx.x;
    const int lane = tid & 63;
    const int m0 = (blockIdx.x >> 1) * 256;
    const int col0 = (blockIdx.x & 1) * 128;
    const half_t* B1_ = B1 + (size_t)col0 * 256;
    const half_t* B2_ = B2 + (size_t)col0 * 256;
    const int l16 = lane & 15, fkg = lane >> 4;
    const int wid = tid >> 6, wm = wid >> 1, wn = wid & 1;  // 4m x 2n
    const int aBase = fkg * 256 + wm * 64 + l16;
    const int bBase = fkg * 128 + wn * 64 + l16;

    f32x4 acc[4][4] = {};

    auto STAGE = [&](int s, int buf) {
        const int kk = (s & 7) * 32;
        const half_t* Bp = (s >> 3) ? B2_ : B1_;
        const half_t* Ap = (s >> 3) ? A2 : A1;
        // B: 1 load/thread (col = tid&127, kg = tid>>7)
        GLOAD_LDS16(Bp + (size_t)(tid & 127) * 256 + kk + (tid >> 7) * 8, &sB[buf][tid]);
        // A: 2 loads/thread
#pragma unroll
        for (int j = 0; j < 2; ++j) {
            int c = tid + j * 512;
            int gr = min(m0 + (c & 255), M - 1);
            GLOAD_LDS16(Ap + (size_t)gr * 256 + kk + (c >> 8) * 8, &sA[buf][c]);
        }
    };

    STAGE(0, 0);
    STAGE(1, 1);

#pragma unroll
    for (int t = 0; t < NSTEPS; ++t) {
        const int buf = t % 3;
        if (t + 1 < NSTEPS) vmwait<3>();
        else vmwait<0>();
        __builtin_amdgcn_s_barrier();
        __builtin_amdgcn_sched_barrier(0);
        if (t + 2 < NSTEPS) STAGE(t + 2, (t + 2) % 3);

        f16x8 ah[4];
#pragma unroll
        for (int mf = 0; mf < 4; ++mf) ah[mf] = sA[buf][aBase + mf * 16];
        __builtin_amdgcn_s_setprio(1);
#pragma unroll
        for (int nf = 0; nf < 4; ++nf) {
            f16x8 bh = sB[buf][bBase + nf * 16];
#pragma unroll
            for (int mf = 0; mf < 4; ++mf)
                acc[mf][nf] = __builtin_amdgcn_mfma_f32_16x16x32_f16(ah[mf], bh, acc[mf][nf], 0, 0, 0);
        }
        __builtin_amdgcn_s_setprio(0);
    }

    // epilogue: row = m0+wm*64+mf*16+(lane>>4)*4+r, col = col0+wn*64+nf*16+l16
#pragma unroll
    for (int mf = 0; mf < 4; ++mf) {
        int row = m0 + wm * 64 + mf * 16 + (lane >> 4) * 4;
#pragma unroll
        for (int nf = 0; nf < 4; ++nf) {
            int col = col0 + wn * 64 + nf * 16 + l16;
            float bv = bias[col];
#pragma unroll
            for (int r = 0; r < 4; ++r) {
                int gr = row + r;
                if (gr < M)
                    C[(size_t)gr * 256 + col] = (half_t)fmaxf(acc[mf][nf][r] + bv, 0.f);
            }
        }
    }
}

// ---------------- fused MLP + head (single-barrier pipeline) ---------------
__global__ __launch_bounds__(512, 4) void k_mlp_head(
    const half_t* __restrict__ A1, const half_t* __restrict__ B1,
    const float* __restrict__ b1, const float* __restrict__ W2,
    const float* __restrict__ b2, float* __restrict__ out, int M) {
    constexpr int NSTEPS = 8;
    __shared__ f16x8 sAB[3 * 512 + 3 * 512];  // 48KB staging; hTile aliases [0,32KB)
    __shared__ float sW2[512];                // W2 [128][4]
    f16x8 (*sA)[512] = (f16x8(*)[512])sAB;
    f16x8 (*sB)[512] = (f16x8(*)[512])(sAB + 3 * 512);
    half_t* hTile = (half_t*)sAB;

    const int tid = threadIdx.x;
    const int lane = tid & 63;
    const int m0 = blockIdx.x * 128;
    const int skg = tid >> 7;
    const int srow = tid & 127;
    const int grow = min(m0 + srow, M - 1);
    const int l16 = lane & 15, fkg = lane >> 4;
    const int wid = tid >> 6, wm = wid >> 2, wn = wid & 3;
    const int aBase = fkg * 128 + wm * 64 + l16;
    const int bBase = fkg * 128 + wn * 32 + l16;

    sW2[tid & 511] = W2[tid & 511];
    asm volatile("s_waitcnt lgkmcnt(0)" ::: "memory");

    f32x4 acc[4][2] = {};

    auto STAGE = [&](int s, int buf) {
        const int kk = s * 32;
        int col = tid & 127;
        int ckg = tid >> 7;
        GLOAD_LDS16(B1 + (size_t)col * 256 + kk + ckg * 8, &sB[buf][tid]);
        GLOAD_LDS16(A1 + (size_t)grow * 256 + kk + skg * 8, &sA[buf][tid]);
    };

    STAGE(0, 0);
    STAGE(1, 1);

#pragma unroll
    for (int t = 0; t < NSTEPS; ++t) {
        const int buf = t % 3;
        if (t + 1 < NSTEPS) vmwait<2>();
        else vmwait<0>();
        __builtin_amdgcn_s_barrier();
        __builtin_amdgcn_sched_barrier(0);
        if (t + 2 < NSTEPS) STAGE(t + 2, (t + 2) % 3);

        f16x8 ah[4];
#pragma unroll
        for (int mf = 0; mf < 4; ++mf) ah[mf] = sA[buf][aBase + mf * 16];
        __builtin_amdgcn_s_setprio(1);
#pragma unroll
        for (int nf = 0; nf < 2; ++nf) {
            f16x8 bh = sB[buf][bBase + nf * 16];
#pragma unroll
            for (int mf = 0; mf < 4; ++mf)
                acc[mf][nf] = __builtin_amdgcn_mfma_f32_16x16x32_f16(ah[mf], bh, acc[mf][nf], 0, 0, 0);
        }
        __builtin_amdgcn_s_setprio(0);
    }

    __syncthreads();
#pragma unroll
    for (int mf = 0; mf < 4; ++mf) {
        int rowl = wm * 64 + mf * 16 + (lane >> 4) * 4;
#pragma unroll
        for (int nf = 0; nf < 2; ++nf) {
            int col = wn * 32 + nf * 16 + l16;
            float bv = b1[col];
#pragma unroll
            for (int r = 0; r < 4; ++r) {
                float v = fmaxf(acc[mf][nf][r] + bv, 0.f);
                hTile[(rowl + r) * 128 + col] = (half_t)v;
            }
        }
    }
    __syncthreads();

    {
        int row = tid >> 2, q = tid & 3;
        const f16x8* hr = (const f16x8*)(hTile + row * 128 + q * 32);
        float px = 0.f, py = 0.f, pz = 0.f, pw = 0.f;
#pragma unroll
        for (int j = 0; j < 4; ++j) {
            f16x8 hv = hr[j];
#pragma unroll
            for (int e = 0; e < 8; ++e) {
                float hf = (float)hv[e];
                const float* wv = sW2 + (q * 32 + j * 8 + e) * 4;
                px += hf * wv[0]; py += hf * wv[1];
                pz += hf * wv[2]; pw += hf * wv[3];
            }
        }
        px += __shfl_xor(px, 1); py += __shfl_xor(py, 1);
        pz += __shfl_xor(pz, 1); pw += __shfl_xor(pw, 1);
        px += __shfl_xor(px, 2); py += __shfl_xor(py, 2);
        pz += __shfl_xor(pz, 2); pw += __shfl_xor(pw, 2);
        int gr = m0 + row;
        if (q == 0 && gr < M) {
            float4 o = {px + b2[0], py + b2[1], pz + b2[2], pw + b2[3]};
            *reinterpret_cast<float4*>(out + (size_t)gr * 4) = o;
        }
    }
}

extern "C" void kernel_launch(void* const* d_in, const int* in_sizes, int n_in,
                              void* d_out, int out_size, void* d_ws, size_t ws_size,
                              hipStream_t stream) {
    const float* x  = (const float*)d_in[0];
    const int*   ei = (const int*)d_in[1];
    const float* Wl = (const float*)d_in[2];
    const float* bl = (const float*)d_in[3];
    const float* Wr = (const float*)d_in[4];
    const float* W1 = (const float*)d_in[5];
    const float* b1 = (const float*)d_in[6];
    const float* W2 = (const float*)d_in[7];
    const float* b2 = (const float*)d_in[8];
    float* out = (float*)d_out;

    char* w = (char*)d_ws;
    size_t o = 0;
    auto alloc = [&](size_t bytes) -> void* {
        void* p = w + o;
        o += (bytes + 255) & ~(size_t)255;
        return p;
    };
    int* deg     = (int*)alloc((size_t)N_NODES * 4);
    int* cursor  = (int*)alloc((size_t)N_NODES * 4);
    int* offsets = (int*)alloc((size_t)N_NODES * 4);
    int* bsum    = (int*)alloc((size_t)NBLK * 4);
    int* bscan   = (int*)alloc((size_t)NBLK * 4);
    int* csr     = (int*)alloc((size_t)N_EDGES * 4);
    half_t* aggH = (half_t*)alloc((size_t)N_NODES * HID * 2);
    half_t* xa   = (half_t*)alloc((size_t)N_NODES * HID * 2);
    half_t* xb   = (half_t*)alloc((size_t)N_NODES * HID * 2);
    half_t* WT   = (half_t*)alloc((size_t)(6 * 65536 + 128 * 256) * 2);

    const int* srcA = ei;
    const int* dstA = ei + N_EDGES;

    k_transw_all<<<1664, 256, 0, stream>>>(Wl, Wr, W1, WT);
    k_tohalf<<<(N_NODES * HID / 8 + 255) / 256, 256, 0, stream>>>(x, xa, N_NODES * HID / 8);

    hipMemsetAsync(deg, 0, (size_t)N_NODES * 4, stream);
    k_count_xcd<<<FILL_CHUNKS * 8, 256, 0, stream>>>(dstA, deg);
    k_blocksum<<<NBLK, 256, 0, stream>>>(deg, bsum);
    k_scan_bsum<<<1, 64, 0, stream>>>(bsum, bscan);
    k_scan_final<<<NBLK, 256, 0, stream>>>(deg, bscan, offsets, cursor);
    k_fill_xcd<<<FILL_CHUNKS * 8, 256, 0, stream>>>(srcA, dstA, cursor, csr);

    const int mtiles128 = (N_NODES + 127) / 128;  // 782
    const int mtiles256 = (N_NODES + 255) / 256;  // 391
    half_t* cur = xa;
    half_t* nxt = xb;
    for (int l = 0; l < 3; ++l) {
        k_aggregate_h<<<N_NODES / 4, 256, 0, stream>>>(cur, offsets, deg, csr, aggH);
        // nxt(fp16) = relu(bl + agg@Wl + cur@Wr), 256x128 tiles, 2 col-blocks
        k_gemm_l<<<mtiles256 * 2, 512, 0, stream>>>(
            aggH, WT + (size_t)l * 65536, cur, WT + (size_t)(3 + l) * 65536,
            bl + (size_t)l * 256, nxt, N_NODES);
        half_t* tmp = cur; cur = nxt; nxt = tmp;
    }
    // fused: out = relu(cur@W1 + b1) @ W2 + b2
    k_mlp_head<<<mtiles128, 512, 0, stream>>>(
        cur, WT + (size_t)6 * 65536, b1, W2, b2, out, N_NODES);
}

// Round 16
// 752.651 us; speedup vs baseline: 1.0564x; 1.0564x over previous
//
#include <hip/hip_runtime.h>

#define N_NODES 100000
#define N_EDGES 1600000
#define HID 256

typedef _Float16 half_t;
using f16x8 = __attribute__((ext_vector_type(8))) half_t;
using f16x4 = __attribute__((ext_vector_type(4))) half_t;
using f32x4 = __attribute__((ext_vector_type(4))) float;

constexpr int SCAN_CHUNK = 1024;
constexpr int NBLK = (N_NODES + SCAN_CHUNK - 1) / SCAN_CHUNK; // 98
constexpr int FILL_EPB = 4096;
constexpr int FILL_CHUNKS = (N_EDGES + FILL_EPB - 1) / FILL_EPB; // 391
constexpr int PREP_TOHALF = N_NODES * HID / 8 / 256;            // 12500
constexpr int PREP_TRANSW = 1664;
constexpr int PREP_ZERO = 98;

#define GLOAD_LDS16(gp, lp)                                                    \
    __builtin_amdgcn_global_load_lds(                                         \
        (const __attribute__((address_space(1))) void*)(gp),                  \
        (__attribute__((address_space(3))) void*)(lp), 16, 0, 0)

template <int N>
__device__ __forceinline__ void vmwait() {
    asm volatile("s_waitcnt vmcnt(%0)" :: "n"(N) : "memory");
}

// ---------------- fused prep: x->fp16 | weight transposes | deg zero -------
// WT layout: [0,3)*65536: WlT[l]; [3,6)*65536: WrT[l]; 6*65536: W1T (128x256)
__global__ void k_prep(const float* __restrict__ x, half_t* __restrict__ xh,
                       const float* __restrict__ Wl, const float* __restrict__ Wr,
                       const float* __restrict__ W1, half_t* __restrict__ WT,
                       int* __restrict__ deg) {
    int b = blockIdx.x;
    int k = threadIdx.x;
    if (b < PREP_TOHALF) {
        int i = b * 256 + k;
        float4 a = *reinterpret_cast<const float4*>(x + (size_t)i * 8);
        float4 c = *reinterpret_cast<const float4*>(x + (size_t)i * 8 + 4);
        f16x8 h;
        h[0] = (half_t)a.x; h[1] = (half_t)a.y; h[2] = (half_t)a.z; h[3] = (half_t)a.w;
        h[4] = (half_t)c.x; h[5] = (half_t)c.y; h[6] = (half_t)c.z; h[7] = (half_t)c.w;
        *reinterpret_cast<f16x8*>(xh + (size_t)i * 8) = h;
    } else if (b < PREP_TOHALF + PREP_TRANSW) {
        int bb = b - PREP_TOHALF;
        if (bb < 768) {
            int l = bb >> 8, col = bb & 255;
            WT[(size_t)l * 65536 + col * 256 + k] = (half_t)Wl[(size_t)l * 65536 + k * 256 + col];
        } else if (bb < 1536) {
            int l = (bb - 768) >> 8, col = bb & 255;
            WT[(size_t)(3 + l) * 65536 + col * 256 + k] = (half_t)Wr[(size_t)l * 65536 + k * 256 + col];
        } else {
            int col = bb - 1536;
            WT[(size_t)6 * 65536 + col * 256 + k] = (half_t)W1[(size_t)k * 128 + col];
        }
    } else {
        int bb = b - PREP_TOHALF - PREP_TRANSW;
        int base = bb * 1024 + k * 4;
#pragma unroll
        for (int e = 0; e < 4; ++e) {
            int idx = base + e;
            if (idx < N_NODES) deg[idx] = 0;
        }
    }
}

// ---------------- CSR build ----------------
__global__ __launch_bounds__(256) void k_count_xcd(
    const int* __restrict__ dst, int* __restrict__ deg) {
    const int part = blockIdx.x & 7;
    const int chunk = blockIdx.x >> 3;
    const int lo = part * (N_NODES / 8);
    const int hi = lo + (N_NODES / 8);
    const int ebeg = chunk * FILL_EPB + threadIdx.x;
    const int eend = min((chunk + 1) * FILL_EPB, N_EDGES);
    for (int e = ebeg; e < eend; e += 256) {
        int d = dst[e];
        if (d >= lo && d < hi) atomicAdd(&deg[d], 1);
    }
}

__global__ void k_blocksum(const int* __restrict__ deg, int* __restrict__ bsum) {
    __shared__ int sm[4];
    int b = blockIdx.x, t = threadIdx.x;
    int base = b * SCAN_CHUNK;
    int s = 0;
    for (int i = 0; i < 4; ++i) {
        int idx = base + t + i * 256;
        if (idx < N_NODES) s += deg[idx];
    }
    for (int off = 32; off; off >>= 1) s += __shfl_down(s, off);
    if ((t & 63) == 0) sm[t >> 6] = s;
    __syncthreads();
    if (t == 0) bsum[b] = sm[0] + sm[1] + sm[2] + sm[3];
}

// parallel 98-element exclusive scan (one 128-thread block)
__global__ void k_scan_bsum(const int* __restrict__ bsum, int* __restrict__ bscan) {
    __shared__ int sm[128];
    int t = threadIdx.x;
    int mine = (t < NBLK) ? bsum[t] : 0;
    sm[t] = mine;
    __syncthreads();
    for (int off = 1; off < 128; off <<= 1) {
        int v = (t >= off) ? sm[t - off] : 0;
        __syncthreads();
        sm[t] += v;
        __syncthreads();
    }
    if (t < NBLK) bscan[t] = sm[t] - mine;
}

__global__ void k_scan_final(const int* __restrict__ deg, const int* __restrict__ bscan,
                             int* __restrict__ offsets, int* __restrict__ cursor) {
    __shared__ int sm[256];
    int b = blockIdx.x, t = threadIdx.x;
    int base = b * SCAN_CHUNK + t * 4;
    int c[4];
    for (int e = 0; e < 4; ++e) {
        int idx = base + e;
        c[e] = (idx < N_NODES) ? deg[idx] : 0;
    }
    int s = c[0] + c[1] + c[2] + c[3];
    sm[t] = s;
    __syncthreads();
    for (int off = 1; off < 256; off <<= 1) {
        int v = (t >= off) ? sm[t - off] : 0;
        __syncthreads();
        sm[t] += v;
        __syncthreads();
    }
    int run = sm[t] - s + bscan[b];
    for (int e = 0; e < 4; ++e) {
        int idx = base + e;
        if (idx < N_NODES) { offsets[idx] = run; cursor[idx] = run; }
        run += c[e];
    }
}

// XCD-partitioned fill (R10 win)
__global__ __launch_bounds__(256) void k_fill_xcd(
    const int* __restrict__ src, const int* __restrict__ dst,
    int* __restrict__ cursor, int* __restrict__ csr) {
    const int part = blockIdx.x & 7;
    const int chunk = blockIdx.x >> 3;
    const int lo = part * (N_NODES / 8);
    const int hi = lo + (N_NODES / 8);
    const int ebeg = chunk * FILL_EPB + threadIdx.x;
    const int eend = min((chunk + 1) * FILL_EPB, N_EDGES);
    for (int e = ebeg; e < eend; e += 256) {
        int d = dst[e];
        if (d >= lo && d < hi) {
            int pos = atomicAdd(&cursor[d], 1);
            csr[pos] = src[e];
        }
    }
}

// ---------------- mean aggregation -> fp16 (at line-rate floor) -----------
__global__ __launch_bounds__(256) void k_aggregate_h(
    const half_t* __restrict__ xh, const int* __restrict__ offsets,
    const int* __restrict__ deg, const int* __restrict__ csr,
    half_t* __restrict__ aggH) {
    int wave = threadIdx.x >> 6;
    int lane = threadIdx.x & 63;
    int node = blockIdx.x * 4 + wave;
    int off = offsets[node];
    int dg = deg[node];
    const size_t lo4 = (size_t)lane * 4;
    float4 a0 = {0.f, 0.f, 0.f, 0.f}, a1 = a0, a2 = a0, a3 = a0;
    int j = 0;
    for (; j + 4 <= dg; j += 4) {
        int s0 = csr[off + j + 0];
        int s1 = csr[off + j + 1];
        int s2 = csr[off + j + 2];
        int s3 = csr[off + j + 3];
        f16x4 v0 = *reinterpret_cast<const f16x4*>(xh + (size_t)s0 * HID + lo4);
        f16x4 v1 = *reinterpret_cast<const f16x4*>(xh + (size_t)s1 * HID + lo4);
        f16x4 v2 = *reinterpret_cast<const f16x4*>(xh + (size_t)s2 * HID + lo4);
        f16x4 v3 = *reinterpret_cast<const f16x4*>(xh + (size_t)s3 * HID + lo4);
        a0.x += (float)v0[0]; a0.y += (float)v0[1]; a0.z += (float)v0[2]; a0.w += (float)v0[3];
        a1.x += (float)v1[0]; a1.y += (float)v1[1]; a1.z += (float)v1[2]; a1.w += (float)v1[3];
        a2.x += (float)v2[0]; a2.y += (float)v2[1]; a2.z += (float)v2[2]; a2.w += (float)v2[3];
        a3.x += (float)v3[0]; a3.y += (float)v3[1]; a3.z += (float)v3[2]; a3.w += (float)v3[3];
    }
    for (; j < dg; ++j) {
        int s = csr[off + j];
        f16x4 v = *reinterpret_cast<const f16x4*>(xh + (size_t)s * HID + lo4);
        a0.x += (float)v[0]; a0.y += (float)v[1]; a0.z += (float)v[2]; a0.w += (float)v[3];
    }
    float av[4];
    av[0] = (a0.x + a1.x) + (a2.x + a3.x);
    av[1] = (a0.y + a1.y) + (a2.y + a3.y);
    av[2] = (a0.z + a1.z) + (a2.z + a3.z);
    av[3] = (a0.w + a1.w) + (a2.w + a3.w);
    float inv = 1.0f / (float)(dg > 0 ? dg : 1);
    f16x4 hi;
#pragma unroll
    for (int c = 0; c < 4; ++c) hi[c] = (half_t)(av[c] * inv);
    *reinterpret_cast<f16x4*>(aggH + (size_t)node * HID + lo4) = hi;
}

// ---------------- layer GEMM: 256x256 tile, SINGLE-barrier (R14 config) ----
// C[M][256] = relu(bias + A1@B1 + A2@B2), K=256/op, fp16 in/out, fp32 acc.
// A,B both 3-buf LDS (96KB), prefetch depth 2. Per step t:
//   vmwait<4>; s_barrier; STAGE(t+2); compute(t). One barrier/step.
__global__ __launch_bounds__(512, 2) void k_gemm_l(
    const half_t* __restrict__ A1, const half_t* __restrict__ B1,
    const half_t* __restrict__ A2, const half_t* __restrict__ B2,
    const float* __restrict__ bias, half_t* __restrict__ C, int M) {
    constexpr int NSTEPS = 16;
    __shared__ f16x8 sA[3][1024];   // [kg(4)][row(256)]
    __shared__ f16x8 sB[3][1024];   // [kg(4)][col(256)]

    const int tid = threadIdx.x;
    const int lane = tid & 63;
    const int m0 = blockIdx.x * 256;
    const int l16 = lane & 15, fkg = lane >> 4;
    const int wid = tid >> 6, wm = wid >> 1, wn = wid & 1;  // 4m x 2n
    const int aBase = fkg * 256 + wm * 64 + l16;
    const int bBase = fkg * 256 + wn * 128 + l16;

    f32x4 acc[4][8] = {};

    auto STAGE = [&](int s, int buf) {
        const int kk = (s & 7) * 32;
        const half_t* Bp = (s >> 3) ? B2 : B1;
        const half_t* Ap = (s >> 3) ? A2 : A1;
#pragma unroll
        for (int j = 0; j < 2; ++j) {
            int c = tid + j * 512;
            GLOAD_LDS16(Bp + (size_t)(c & 255) * 256 + kk + (c >> 8) * 8, &sB[buf][c]);
        }
#pragma unroll
        for (int j = 0; j < 2; ++j) {
            int c = tid + j * 512;
            int gr = min(m0 + (c & 255), M - 1);
            GLOAD_LDS16(Ap + (size_t)gr * 256 + kk + (c >> 8) * 8, &sA[buf][c]);
        }
    };

    STAGE(0, 0);
    STAGE(1, 1);

#pragma unroll
    for (int t = 0; t < NSTEPS; ++t) {
        const int buf = t % 3;
        if (t + 1 < NSTEPS) vmwait<4>();
        else vmwait<0>();
        __builtin_amdgcn_s_barrier();
        __builtin_amdgcn_sched_barrier(0);
        if (t + 2 < NSTEPS) STAGE(t + 2, (t + 2) % 3);

        f16x8 ah[4];
#pragma unroll
        for (int mf = 0; mf < 4; ++mf) ah[mf] = sA[buf][aBase + mf * 16];
        __builtin_amdgcn_s_setprio(1);
#pragma unroll
        for (int nf = 0; nf < 8; ++nf) {
            f16x8 bh = sB[buf][bBase + nf * 16];
#pragma unroll
            for (int mf = 0; mf < 4; ++mf)
                acc[mf][nf] = __builtin_amdgcn_mfma_f32_16x16x32_f16(ah[mf], bh, acc[mf][nf], 0, 0, 0);
        }
        __builtin_amdgcn_s_setprio(0);
    }

    // epilogue: row = m0+wm*64+mf*16+(lane>>4)*4+r, col = wn*128+nf*16+l16
#pragma unroll
    for (int mf = 0; mf < 4; ++mf) {
        int row = m0 + wm * 64 + mf * 16 + (lane >> 4) * 4;
#pragma unroll
        for (int nf = 0; nf < 8; ++nf) {
            int col = wn * 128 + nf * 16 + l16;
            float bv = bias[col];
#pragma unroll
            for (int r = 0; r < 4; ++r) {
                int gr = row + r;
                if (gr < M)
                    C[(size_t)gr * 256 + col] = (half_t)fmaxf(acc[mf][nf][r] + bv, 0.f);
            }
        }
    }
}

// ---------------- fused MLP + head (single-barrier pipeline) ---------------
__global__ __launch_bounds__(512, 4) void k_mlp_head(
    const half_t* __restrict__ A1, const half_t* __restrict__ B1,
    const float* __restrict__ b1, const float* __restrict__ W2,
    const float* __restrict__ b2, float* __restrict__ out, int M) {
    constexpr int NSTEPS = 8;
    __shared__ f16x8 sAB[3 * 512 + 3 * 512];  // 48KB staging; hTile aliases [0,32KB)
    __shared__ float sW2[512];                // W2 [128][4]
    f16x8 (*sA)[512] = (f16x8(*)[512])sAB;
    f16x8 (*sB)[512] = (f16x8(*)[512])(sAB + 3 * 512);
    half_t* hTile = (half_t*)sAB;

    const int tid = threadIdx.x;
    const int lane = tid & 63;
    const int m0 = blockIdx.x * 128;
    const int skg = tid >> 7;
    const int srow = tid & 127;
    const int grow = min(m0 + srow, M - 1);
    const int l16 = lane & 15, fkg = lane >> 4;
    const int wid = tid >> 6, wm = wid >> 2, wn = wid & 3;
    const int aBase = fkg * 128 + wm * 64 + l16;
    const int bBase = fkg * 128 + wn * 32 + l16;

    sW2[tid & 511] = W2[tid & 511];
    asm volatile("s_waitcnt lgkmcnt(0)" ::: "memory");

    f32x4 acc[4][2] = {};

    auto STAGE = [&](int s, int buf) {
        const int kk = s * 32;
        int col = tid & 127;
        int ckg = tid >> 7;
        GLOAD_LDS16(B1 + (size_t)col * 256 + kk + ckg * 8, &sB[buf][tid]);
        GLOAD_LDS16(A1 + (size_t)grow * 256 + kk + skg * 8, &sA[buf][tid]);
    };

    STAGE(0, 0);
    STAGE(1, 1);

#pragma unroll
    for (int t = 0; t < NSTEPS; ++t) {
        const int buf = t % 3;
        if (t + 1 < NSTEPS) vmwait<2>();
        else vmwait<0>();
        __builtin_amdgcn_s_barrier();
        __builtin_amdgcn_sched_barrier(0);
        if (t + 2 < NSTEPS) STAGE(t + 2, (t + 2) % 3);

        f16x8 ah[4];
#pragma unroll
        for (int mf = 0; mf < 4; ++mf) ah[mf] = sA[buf][aBase + mf * 16];
        __builtin_amdgcn_s_setprio(1);
#pragma unroll
        for (int nf = 0; nf < 2; ++nf) {
            f16x8 bh = sB[buf][bBase + nf * 16];
#pragma unroll
            for (int mf = 0; mf < 4; ++mf)
                acc[mf][nf] = __builtin_amdgcn_mfma_f32_16x16x32_f16(ah[mf], bh, acc[mf][nf], 0, 0, 0);
        }
        __builtin_amdgcn_s_setprio(0);
    }

    __syncthreads();
#pragma unroll
    for (int mf = 0; mf < 4; ++mf) {
        int rowl = wm * 64 + mf * 16 + (lane >> 4) * 4;
#pragma unroll
        for (int nf = 0; nf < 2; ++nf) {
            int col = wn * 32 + nf * 16 + l16;
            float bv = b1[col];
#pragma unroll
            for (int r = 0; r < 4; ++r) {
                float v = fmaxf(acc[mf][nf][r] + bv, 0.f);
                hTile[(rowl + r) * 128 + col] = (half_t)v;
            }
        }
    }
    __syncthreads();

    {
        int row = tid >> 2, q = tid & 3;
        const f16x8* hr = (const f16x8*)(hTile + row * 128 + q * 32);
        float px = 0.f, py = 0.f, pz = 0.f, pw = 0.f;
#pragma unroll
        for (int j = 0; j < 4; ++j) {
            f16x8 hv = hr[j];
#pragma unroll
            for (int e = 0; e < 8; ++e) {
                float hf = (float)hv[e];
                const float* wv = sW2 + (q * 32 + j * 8 + e) * 4;
                px += hf * wv[0]; py += hf * wv[1];
                pz += hf * wv[2]; pw += hf * wv[3];
            }
        }
        px += __shfl_xor(px, 1); py += __shfl_xor(py, 1);
        pz += __shfl_xor(pz, 1); pw += __shfl_xor(pw, 1);
        px += __shfl_xor(px, 2); py += __shfl_xor(py, 2);
        pz += __shfl_xor(pz, 2); pw += __shfl_xor(pw, 2);
        int gr = m0 + row;
        if (q == 0 && gr < M) {
            float4 o = {px + b2[0], py + b2[1], pz + b2[2], pw + b2[3]};
            *reinterpret_cast<float4*>(out + (size_t)gr * 4) = o;
        }
    }
}

extern "C" void kernel_launch(void* const* d_in, const int* in_sizes, int n_in,
                              void* d_out, int out_size, void* d_ws, size_t ws_size,
                              hipStream_t stream) {
    const float* x  = (const float*)d_in[0];
    const int*   ei = (const int*)d_in[1];
    const float* Wl = (const float*)d_in[2];
    const float* bl = (const float*)d_in[3];
    const float* Wr = (const float*)d_in[4];
    const float* W1 = (const float*)d_in[5];
    const float* b1 = (const float*)d_in[6];
    const float* W2 = (const float*)d_in[7];
    const float* b2 = (const float*)d_in[8];
    float* out = (float*)d_out;

    char* w = (char*)d_ws;
    size_t o = 0;
    auto alloc = [&](size_t bytes) -> void* {
        void* p = w + o;
        o += (bytes + 255) & ~(size_t)255;
        return p;
    };
    int* deg     = (int*)alloc((size_t)N_NODES * 4);
    int* cursor  = (int*)alloc((size_t)N_NODES * 4);
    int* offsets = (int*)alloc((size_t)N_NODES * 4);
    int* bsum    = (int*)alloc((size_t)NBLK * 4);
    int* bscan   = (int*)alloc((size_t)NBLK * 4);
    int* csr     = (int*)alloc((size_t)N_EDGES * 4);
    half_t* aggH = (half_t*)alloc((size_t)N_NODES * HID * 2);
    half_t* xa   = (half_t*)alloc((size_t)N_NODES * HID * 2);
    half_t* xb   = (half_t*)alloc((size_t)N_NODES * HID * 2);
    half_t* WT   = (half_t*)alloc((size_t)(6 * 65536 + 128 * 256) * 2);

    const int* srcA = ei;
    const int* dstA = ei + N_EDGES;

    // fused prep: x->fp16, weight transposes, deg zeroing (one launch)
    k_prep<<<PREP_TOHALF + PREP_TRANSW + PREP_ZERO, 256, 0, stream>>>(
        x, xa, Wl, Wr, W1, WT, deg);

    k_count_xcd<<<FILL_CHUNKS * 8, 256, 0, stream>>>(dstA, deg);
    k_blocksum<<<NBLK, 256, 0, stream>>>(deg, bsum);
    k_scan_bsum<<<1, 128, 0, stream>>>(bsum, bscan);
    k_scan_final<<<NBLK, 256, 0, stream>>>(deg, bscan, offsets, cursor);
    k_fill_xcd<<<FILL_CHUNKS * 8, 256, 0, stream>>>(srcA, dstA, cursor, csr);

    const int mtiles128 = (N_NODES + 127) / 128;  // 782
    const int mtiles256 = (N_NODES + 255) / 256;  // 391
    half_t* cur = xa;
    half_t* nxt = xb;
    for (int l = 0; l < 3; ++l) {
        k_aggregate_h<<<N_NODES / 4, 256, 0, stream>>>(cur, offsets, deg, csr, aggH);
        // nxt(fp16) = relu(bl + agg@Wl + cur@Wr), 256x256 tiles (R14 config)
        k_gemm_l<<<mtiles256, 512, 0, stream>>>(
            aggH, WT + (size_t)l * 65536, cur, WT + (size_t)(3 + l) * 65536,
            bl + (size_t)l * 256, nxt, N_NODES);
        half_t* tmp = cur; cur = nxt; nxt = tmp;
    }
    // fused: out = relu(cur@W1 + b1) @ W2 + b2
    k_mlp_head<<<mtiles128, 512, 0, stream>>>(
        cur, WT + (size_t)6 * 65536, b1, W2, b2, out, N_NODES);
}